// Round 1
// baseline (90.123 us; speedup 1.0000x reference)
//
#include <hip/hip_runtime.h>

// PhysicalCircleLayer on MI355X.
// One block per batch (B=1024), 256 threads. Each thread consumes float4
// chunks of the 10000-pixel seg_map (stride-256 over 2500 float4s).
//
// Exactness notes (must track fp32 reference):
//  - (pix-b)/W has only 100 distinct values per axis -> precomputed in LDS
//    with IEEE '/'  (bit-identical to the reference's elementwise divide).
//  - moving_vector = (t7+cp)-(t0+cp) computed in that exact order.
//  - __fmul_rn/__fadd_rn block fma contraction on norms (match mul,mul,add).
//  - bin computed geometrically (exact octant boundaries at x=0,y=0,|x|=|y|);
//    reference's fp32 atan2/mod/div boundaries coincide except within ~1ulp
//    of angle (fp32(m*pi/4) boundary constants are exact multiples of
//    fp32(2pi)/8), negligible under the 1.64 absmax threshold.
//  - equ_dis uses fast divide: ~1e-7 relative error, value-level only.

#define INFV 1.0e9f

__global__ __launch_bounds__(256)
void pcl_kernel(const float* __restrict__ seg_maps,
                const float* __restrict__ paras,
                const float* __restrict__ traj,
                const float* __restrict__ cpos,
                float* __restrict__ out)
{
    const int b    = blockIdx.x;
    const int tid  = threadIdx.x;
    const int lane = tid & 63;
    const int wave = tid >> 6;

    __shared__ __align__(16) float sA[100];   // (i - b0)/W0
    __shared__ __align__(16) float sB[100];   // (j - b1)/W1
    __shared__ float sred[4][8];

    const float* pp = paras + b * 6;
    const float W0 = pp[0], W1 = pp[1];
    const float bb0 = pp[2], bb1 = pp[3];
    const bool  swp = (pp[4] == 1.0f);
    const float cp0 = cpos[b * 2 + 0];
    const float cp1 = cpos[b * 2 + 1];

    // moving_length: _obs = traj + cp done in fp32 BEFORE the subtraction.
    const float* tp  = traj + b * 16;
    const float o00 = __fadd_rn(tp[0],  cp0);
    const float o01 = __fadd_rn(tp[1],  cp1);
    const float o70 = __fadd_rn(tp[14], cp0);
    const float o71 = __fadd_rn(tp[15], cp1);
    const float mv0 = __fsub_rn(o70, o00);
    const float mv1 = __fsub_rn(o71, o01);
    const float mlen = sqrtf(__fadd_rn(__fmul_rn(mv0, mv0), __fmul_rn(mv1, mv1)));
    const float r    = __fmul_rn(2.0f, mlen);

    if (tid < 100) {
        sA[tid] = ((float)tid - bb0) / W0;           // IEEE divide, matches ref
    } else if (tid < 200) {
        const int j = tid - 100;
        sB[j] = ((float)j - bb1) / W1;
    }
    __syncthreads();

    float m[8];
#pragma unroll
    for (int o = 0; o < 8; ++o) m[o] = INFV;

    const float* smap = seg_maps + (size_t)b * 10000;

    for (int q = tid; q < 2500; q += 256) {
        const int k0 = q << 2;
        const int i  = k0 / 100;          // magic-mul divide
        const int j0 = k0 - i * 100;      // multiple of 4 (100 % 4 == 0)

        const float4 mp = *reinterpret_cast<const float4*>(smap + k0);
        const float  av = sA[i];
        const float4 bv = *reinterpret_cast<const float4*>(&sB[j0]);

        const float mapv[4] = {mp.x, mp.y, mp.z, mp.w};
        const float bvs[4]  = {bv.x, bv.y, bv.z, bv.w};
        float xs[4], ys[4], dist[4];
        bool  val[4];
        bool  anyv = false;
#pragma unroll
        for (int c = 0; c < 4; ++c) {
            const float x = __fsub_rn(swp ? bvs[c] : av, cp0);
            const float y = __fsub_rn(swp ? av : bvs[c], cp1);
            xs[c] = x; ys[c] = y;
            const float d2 = __fadd_rn(__fmul_rn(x, x), __fmul_rn(y, y));
            const float dd = sqrtf(d2);
            dist[c] = dd;
            const bool v = (mapv[c] > 0.05f) && (dd <= r);
            val[c] = v;
            anyv |= v;
        }
        // Whole-wave skip: most of the map is outside the vision radius.
        if (__any(anyv)) {
#pragma unroll
            for (int c = 0; c < 4; ++c) {
                const float x = xs[c], y = ys[c];
                // bin = floor(mod(atan2(x,y), 2pi) / (pi/4)), geometric form.
                const int bin =
                    (y > 0.0f)
                      ? ((x >= 0.0f) ? ((x < y) ? 0 : 1)
                                     : ((-x > y) ? 6 : 7))
                      : ((y < 0.0f)
                           ? ((x > 0.0f) ? ((x > -y) ? 2 : 3)
                                         : ((x > y) ? 4 : 5))
                           : ((x > 0.0f) ? 2
                              : ((x < 0.0f) ? 6
                                 : ((__float_as_uint(y) & 0x80000000u) ? 4 : 0))));
                const float e  = __fdividef(__fadd_rn(dist[c], 1.0e-8f),
                                            __fadd_rn(mapv[c], 1.0e-8f));
                const float dv = val[c] ? e : INFV;
#pragma unroll
                for (int o = 0; o < 8; ++o)
                    m[o] = fminf(m[o], (bin == o) ? dv : INFV);
            }
        }
    }

    // wave-level min reduce, then cross-wave via LDS
#pragma unroll
    for (int o = 0; o < 8; ++o) {
        float v = m[o];
#pragma unroll
        for (int off = 32; off > 0; off >>= 1)
            v = fminf(v, __shfl_down(v, off, 64));
        if (lane == 0) sred[wave][o] = v;
    }
    __syncthreads();

    if (tid < 16) {
        float vel = 0.0f, md = 0.0f, dir = 0.0f;
        if (tid < 8) {
            const float v = fminf(fminf(sred[0][tid], sred[1][tid]),
                                  fminf(sred[2][tid], sred[3][tid]));
            if (v < INFV) {
                vel = mlen;
                md  = v;
                // bin_centers = fp32(2pi) * ((p+0.5)/8)
                dir = __fmul_rn(6.28318530717958647692f,
                                __fmul_rn((float)tid + 0.5f, 0.125f));
            }
        }
        float* po = out + (size_t)b * 48 + tid * 3;
        po[0] = vel; po[1] = md; po[2] = dir;
    }
}

extern "C" void kernel_launch(void* const* d_in, const int* in_sizes, int n_in,
                              void* d_out, int out_size, void* d_ws, size_t ws_size,
                              hipStream_t stream) {
    const float* seg_maps = (const float*)d_in[0];
    const float* paras    = (const float*)d_in[1];   // (B,6): W0 W1 b0 b1 ord0 ord1
    const float* traj     = (const float*)d_in[2];   // (B,8,2)
    const float* cpos     = (const float*)d_in[3];   // (B,1,2)
    float* out            = (float*)d_out;           // (B,16,3) fp32

    const int B = in_sizes[1] / 6;
    pcl_kernel<<<B, 256, 0, stream>>>(seg_maps, paras, traj, cpos, out);
}

// Round 2
// 86.910 us; speedup vs baseline: 1.0370x; 1.0370x over previous
//
#include <hip/hip_runtime.h>

// PhysicalCircleLayer on MI355X — round 2.
// One block per batch (B=1024), 256 threads, float4 sweep of the 100x100 map.
//
// Exactness (tracks fp32 numpy reference bit-for-bit, round-1 absmax 0.0):
//  - (pix-b)/W precomputed in LDS with IEEE '/' (100 distinct values/axis).
//  - moving_vector = (t7+cp)-(t0+cp) in that order; _rn ops block fma fusion.
//  - d2 = add_rn(row_term^2, col_term^2): fp32 add is commutative, so the
//    order-swap (order0==1) does not change d2; x/y are swapped only for the
//    bin geometry, which is exact (octant sign/compare tests).
//  - Light path uses a conservative prefilter d2 <= r^2*(1+2e-5): any pixel
//    with fl(sqrt(d2)) <= r satisfies d2 <= r^2*(1+6e-7), so no valid pixel
//    is ever skipped; the heavy path redoes the exact sqrt(d2) <= r test.
//  - equ_dis uses __fdividef (matched bit-exact in round 1; 1.64 abs slack).

#define INFV 1.0e9f

__global__ __launch_bounds__(256)
void pcl_kernel(const float* __restrict__ seg_maps,
                const float* __restrict__ paras,
                const float* __restrict__ traj,
                const float* __restrict__ cpos,
                float* __restrict__ out)
{
    const int b    = blockIdx.x;
    const int tid  = threadIdx.x;
    const int lane = tid & 63;
    const int wave = tid >> 6;

    __shared__ __align__(16) float sRow[100];    // row-axis term (x if !swp, y if swp)
    __shared__ __align__(16) float sCol[100];    // col-axis term (y if !swp, x if swp)
    __shared__ __align__(16) float sCol2[100];   // mul_rn(col term, col term)
    __shared__ float sred[4][8];

    const float* pp = paras + b * 6;
    const float W0 = pp[0], W1 = pp[1];
    const float bb0 = pp[2], bb1 = pp[3];
    const bool  swp = (pp[4] == 1.0f);
    const float cp0 = cpos[b * 2 + 0];
    const float cp1 = cpos[b * 2 + 1];

    // moving_length: _obs = traj + cp in fp32 BEFORE the subtraction.
    const float* tp  = traj + b * 16;
    const float o00 = __fadd_rn(tp[0],  cp0);
    const float o01 = __fadd_rn(tp[1],  cp1);
    const float o70 = __fadd_rn(tp[14], cp0);
    const float o71 = __fadd_rn(tp[15], cp1);
    const float mv0 = __fsub_rn(o70, o00);
    const float mv1 = __fsub_rn(o71, o01);
    const float mlen = sqrtf(__fadd_rn(__fmul_rn(mv0, mv0), __fmul_rn(mv1, mv1)));
    const float r    = __fmul_rn(2.0f, mlen);
    // conservative prefilter radius^2 (margin >> 6e-7 relative, + tiny abs for r==0)
    const float r2m  = __fmul_rn(r, r) * 1.00002f + 1e-30f;

    if (tid < 100) {
        const float a = ((float)tid - bb0) / W0;          // IEEE divide, matches ref
        sRow[tid] = __fsub_rn(a, swp ? cp1 : cp0);
    } else if (tid < 200) {
        const int j = tid - 100;
        const float c = ((float)j - bb1) / W1;            // IEEE divide, matches ref
        const float cv = __fsub_rn(c, swp ? cp0 : cp1);
        sCol[j]  = cv;
        sCol2[j] = __fmul_rn(cv, cv);
    }
    __syncthreads();

    float m[8];
#pragma unroll
    for (int o = 0; o < 8; ++o) m[o] = INFV;

    const float* smap = seg_maps + (size_t)b * 10000;

    for (int q = tid; q < 2500; q += 256) {
        const int k0 = q << 2;
        const int i  = k0 / 100;          // magic-mul divide
        const int j0 = k0 - i * 100;      // multiple of 4 (100 % 4 == 0)

        const float4 mp = *reinterpret_cast<const float4*>(smap + k0);
        const float  rv = sRow[i];
        const float x2r = __fmul_rn(rv, rv);
        const float4 c2 = *reinterpret_cast<const float4*>(&sCol2[j0]);

        const float mapv[4] = {mp.x, mp.y, mp.z, mp.w};
        const float c2s[4]  = {c2.x, c2.y, c2.z, c2.w};
        float d2[4];
        bool  anyp = false;
#pragma unroll
        for (int c = 0; c < 4; ++c) {
            d2[c] = __fadd_rn(x2r, c2s[c]);               // == ref's x*x + y*y
            anyp |= (mapv[c] > 0.05f) && (d2[c] <= r2m);
        }
        // Whole-wave skip: most of the map is outside the vision radius.
        if (__any(anyp)) {
            const float4 cv4 = *reinterpret_cast<const float4*>(&sCol[j0]);
            const float cvs[4] = {cv4.x, cv4.y, cv4.z, cv4.w};
#pragma unroll
            for (int c = 0; c < 4; ++c) {
                const float colv = cvs[c];
                const float x = swp ? colv : rv;
                const float y = swp ? rv : colv;
                const float dd = sqrtf(d2[c]);            // exact, as reference
                const bool val = (mapv[c] > 0.05f) && (dd <= r);
                // bin = floor(mod(atan2(x,y), 2pi) / (pi/4)), geometric form.
                const int bin =
                    (y > 0.0f)
                      ? ((x >= 0.0f) ? ((x < y) ? 0 : 1)
                                     : ((-x > y) ? 6 : 7))
                      : ((y < 0.0f)
                           ? ((x > 0.0f) ? ((x > -y) ? 2 : 3)
                                         : ((x > y) ? 4 : 5))
                           : ((x > 0.0f) ? 2
                              : ((x < 0.0f) ? 6
                                 : ((__float_as_uint(y) & 0x80000000u) ? 4 : 0))));
                const float e  = __fdividef(__fadd_rn(dd, 1.0e-8f),
                                            __fadd_rn(mapv[c], 1.0e-8f));
                const float dv = val ? e : INFV;
#pragma unroll
                for (int o = 0; o < 8; ++o)
                    m[o] = fminf(m[o], (bin == o) ? dv : INFV);
            }
        }
    }

    // wave-level min reduce, then cross-wave via LDS
#pragma unroll
    for (int o = 0; o < 8; ++o) {
        float v = m[o];
#pragma unroll
        for (int off = 32; off > 0; off >>= 1)
            v = fminf(v, __shfl_down(v, off, 64));
        if (lane == 0) sred[wave][o] = v;
    }
    __syncthreads();

    if (tid < 16) {
        float vel = 0.0f, md = 0.0f, dir = 0.0f;
        if (tid < 8) {
            const float v = fminf(fminf(sred[0][tid], sred[1][tid]),
                                  fminf(sred[2][tid], sred[3][tid]));
            if (v < INFV) {
                vel = mlen;
                md  = v;
                dir = __fmul_rn(6.28318530717958647692f,
                                __fmul_rn((float)tid + 0.5f, 0.125f));
            }
        }
        float* po = out + (size_t)b * 48 + tid * 3;
        po[0] = vel; po[1] = md; po[2] = dir;
    }
}

extern "C" void kernel_launch(void* const* d_in, const int* in_sizes, int n_in,
                              void* d_out, int out_size, void* d_ws, size_t ws_size,
                              hipStream_t stream) {
    const float* seg_maps = (const float*)d_in[0];
    const float* paras    = (const float*)d_in[1];   // (B,6): W0 W1 b0 b1 ord0 ord1
    const float* traj     = (const float*)d_in[2];   // (B,8,2)
    const float* cpos     = (const float*)d_in[3];   // (B,1,2)
    float* out            = (float*)d_out;           // (B,16,3) fp32

    const int B = in_sizes[1] / 6;
    pcl_kernel<<<B, 256, 0, stream>>>(seg_maps, paras, traj, cpos, out);
}